// Round 4
// baseline (386.068 us; speedup 1.0000x reference)
//
#include <hip/hip_runtime.h>
#include <hip/hip_bf16.h>

// ---- problem shape (fixed) ----
#define H_ATT   16
#define DH      128
#define DMODEL  2048
#define DLAT    512
#define NB      2
#define SEQ     2048
#define MROWS   (NB * SEQ)   // 4096
#define NQZ     (DMODEL + DLAT)   // 2560
#define NKV     (2 * DMODEL)      // 4096

// (1/sqrt(128)) * log2(e): folded into w_q/b_q so scores are exp2-ready
#define SCL2 0.12751744f

typedef __bf16          bf16x8_t __attribute__((ext_vector_type(8)));
typedef float           f32x4_t  __attribute__((ext_vector_type(4)));
typedef unsigned short  u16x4_t  __attribute__((ext_vector_type(4)));

#if __has_builtin(__builtin_amdgcn_exp2f)
#define EXP2F(x) __builtin_amdgcn_exp2f(x)
#else
#define EXP2F(x) exp2f(x)
#endif

__device__ __forceinline__ unsigned short f2bf_u16(float f) {
  union { __bf16 b; unsigned short u; } cv; cv.b = (__bf16)f; return cv.u;
}

// async global->LDS, 16B per lane (dest = wave-uniform base + lane*16)
__device__ __forceinline__ void async_copy16(const __bf16* g, __bf16* l) {
  __builtin_amdgcn_global_load_lds(
      (const __attribute__((address_space(1))) unsigned int*)g,
      (__attribute__((address_space(3))) unsigned int*)l, 16, 0, 0);
}

// ---------------- fused prep: x-cast + 5 weight transposes + bias concat ----------------
#define NB_CAST 8192    // (4096*2048/4)/256
#define NB_WQ   4096
#define NB_WL   1024
#define NB_WK   1024
#define NB_WV   1024
#define NB_WO   4096
#define NB_BIAS 26
#define NB_PREP (NB_CAST + NB_WQ + NB_WL + NB_WK + NB_WV + NB_WO + NB_BIAS)  // 19482

__global__ void prep(const float* __restrict__ x,
                     const float* __restrict__ w_q, const float* __restrict__ w_latent,
                     const float* __restrict__ w_k, const float* __restrict__ w_v,
                     const float* __restrict__ w_o,
                     const float* __restrict__ b_q, const float* __restrict__ b_lat,
                     const float* __restrict__ b_k, const float* __restrict__ b_v,
                     __bf16* __restrict__ xb, __bf16* __restrict__ wqzt,
                     __bf16* __restrict__ wkvt, __bf16* __restrict__ wot,
                     float* __restrict__ bqz, float* __restrict__ bkv) {
  __shared__ float tile[32][33];
  int bi = blockIdx.x;
  int t  = threadIdx.x;

  if (bi < NB_CAST) {                       // ---- cast x -> bf16
    int i = bi * 256 + t;
    float4 v = ((const float4*)x)[i];
    ushort4 o;
    o.x = f2bf_u16(v.x); o.y = f2bf_u16(v.y); o.z = f2bf_u16(v.z); o.w = f2bf_u16(v.w);
    ((ushort4*)xb)[i] = o;
    return;
  }
  bi -= NB_CAST;

  const float* in = nullptr; __bf16* out = nullptr;
  int R = 0, C = 0, bx = 0, by = 0; float scale = 1.f;
  if (bi < NB_WQ) {                         // ---- w_q^T (scaled)
    in = w_q; out = wqzt; R = DMODEL; C = DMODEL; scale = SCL2;
    bx = bi & 63; by = bi >> 6;
  } else if ((bi -= NB_WQ) < NB_WL) {       // ---- w_latent^T
    in = w_latent; out = wqzt + (size_t)DMODEL * DMODEL; R = DMODEL; C = DLAT;
    bx = bi & 15; by = bi >> 4;
  } else if ((bi -= NB_WL) < NB_WK) {       // ---- w_k^T per head
    int h = bi >> 6, rem = bi & 63;
    in = w_k + (size_t)h * DLAT * DH; out = wkvt + (size_t)h * DH * DLAT;
    R = DLAT; C = DH; bx = rem & 3; by = rem >> 2;
  } else if ((bi -= NB_WK) < NB_WV) {       // ---- w_v^T per head
    int h = bi >> 6, rem = bi & 63;
    in = w_v + (size_t)h * DLAT * DH;
    out = wkvt + (size_t)DMODEL * DLAT + (size_t)h * DH * DLAT;
    R = DLAT; C = DH; bx = rem & 3; by = rem >> 2;
  } else if ((bi -= NB_WV) < NB_WO) {       // ---- w_o^T
    in = w_o; out = wot; R = DMODEL; C = DMODEL;
    bx = bi & 63; by = bi >> 6;
  } else {                                  // ---- biases
    bi -= NB_WO;
    int idx = bi * 256 + t;
    if (idx < DMODEL)                bqz[idx] = b_q[idx] * SCL2;
    else if (idx < NQZ)              bqz[idx] = b_lat[idx - DMODEL];
    else if (idx < NQZ + DMODEL)     bkv[idx - NQZ] = b_k[idx - NQZ];
    else if (idx < NQZ + NKV)        bkv[idx - NQZ] = b_v[idx - NQZ - DMODEL];
    return;
  }

  int tx = t & 31, ty = t >> 5;   // (32,8)
  const float* ip = in + (size_t)(by * 32) * C + bx * 32;
  #pragma unroll
  for (int i = 0; i < 4; ++i)
    tile[ty + i * 8][tx] = ip[(size_t)(ty + i * 8) * C + tx];
  __syncthreads();
  __bf16* op = out + (size_t)(bx * 32) * R + by * 32;
  #pragma unroll
  for (int i = 0; i < 4; ++i)
    op[(size_t)(ty + i * 8) * R + tx] = (__bf16)(tile[tx][ty + i * 8] * scale);
}

// ---------------- GEMM (m97 structure): C[M,N] = A[M,K] @ Bt[N,K]^T + bias[N] ----------------
// KVDUAL: cols < DMODEL -> normal store to C (k); cols >= DMODEL -> transposed store
// vt[b][col-DMODEL][s] to Cvt (v).
#define BM 128
#define BN 128
#define BK 32

__device__ __forceinline__ void storec(float*  p, float v) { *p = v; }
__device__ __forceinline__ void storec(__bf16* p, float v) { *p = (__bf16)v; }

template <typename OutT, bool KVDUAL>
__global__ __launch_bounds__(256, 2)
void gemm_bt(const __bf16* __restrict__ A, const __bf16* __restrict__ Bt,
             const float* __restrict__ bias, OutT* __restrict__ C,
             __bf16* __restrict__ Cvt,
             int M, int N, int K, int lda, int ldc) {
  __shared__ __align__(16) __bf16 As[BM * BK];
  __shared__ __align__(16) __bf16 Bs[BN * BK];
  const int t    = threadIdx.x;
  const int wave = t >> 6, lane = t & 63;
  const int quad = lane >> 4, l16 = lane & 15;
  const int wm = (wave >> 1) * 64, wn = (wave & 1) * 64;
  const int row0 = blockIdx.y * BM, col0 = blockIdx.x * BN;
  const int srow = t >> 2, skc = t & 3;

  const __bf16* Ag  = A  + (size_t)(row0 + srow)      * lda + skc * 8;
  const __bf16* Ag2 = A  + (size_t)(row0 + srow + 64) * lda + skc * 8;
  const __bf16* Bg  = Bt + (size_t)(col0 + srow)      * K   + skc * 8;
  const __bf16* Bg2 = Bt + (size_t)(col0 + srow + 64) * K   + skc * 8;
  __bf16* Al  = As + t * 8;
  __bf16* Al2 = As + 2048 + t * 8;
  __bf16* Bl  = Bs + t * 8;
  __bf16* Bl2 = Bs + 2048 + t * 8;

  f32x4_t acc[4][4] = {};

  for (int k0 = 0; k0 < K; k0 += BK) {
    async_copy16(Ag  + k0, Al);
    async_copy16(Ag2 + k0, Al2);
    async_copy16(Bg  + k0, Bl);
    async_copy16(Bg2 + k0, Bl2);
    __syncthreads();
    bf16x8_t af[4], bfr[4];
    #pragma unroll
    for (int i = 0; i < 4; ++i)
      af[i] = *(const bf16x8_t*)(As + (wm + i * 16 + l16) * BK + quad * 8);
    #pragma unroll
    for (int j = 0; j < 4; ++j)
      bfr[j] = *(const bf16x8_t*)(Bs + (wn + j * 16 + l16) * BK + quad * 8);
    #pragma unroll
    for (int i = 0; i < 4; ++i)
      #pragma unroll
      for (int j = 0; j < 4; ++j)
        acc[i][j] = __builtin_amdgcn_mfma_f32_16x16x32_bf16(af[i], bfr[j], acc[i][j], 0, 0, 0);
    __syncthreads();
  }

  const bool vmode = KVDUAL && (col0 >= DMODEL);
  // C/D layout: col = lane&15, row = quad*4 + reg
  #pragma unroll
  for (int j = 0; j < 4; ++j) {
    int col = col0 + wn + j * 16 + l16;
    float bj = bias[col];
    #pragma unroll
    for (int i = 0; i < 4; ++i) {
      int row = row0 + wm + i * 16 + quad * 4;
      if (vmode) {
        u16x4_t pw;
        #pragma unroll
        for (int r = 0; r < 4; ++r) pw[r] = f2bf_u16(acc[i][j][r] + bj);
        size_t bb = (size_t)(row >> 11);
        int s = row & (SEQ - 1);
        *(u16x4_t*)(Cvt + bb * ((size_t)DMODEL * SEQ) + (size_t)(col - DMODEL) * SEQ + s) = pw;
      } else {
        #pragma unroll
        for (int r = 0; r < 4; ++r)
          storec(&C[(size_t)(row + r) * ldc + col], acc[i][j][r] + bj);
      }
    }
  }
}

// ---------------- flash attention v4: single barrier per 32-key tile ----------------
// grid (SEQ/128, H, B), block 256 (4 waves): wq = wave>>1 (64q), wk = wd = wave&1.
// Buffers: K x2, V x3, P x2 (8 KB each) -> every producer/consumer pair is separated
// by >=1 barrier, with the tile-(i+1) DMA issued at the top of iter i (in flight a
// full iteration before the drain that precedes its consumption).
#define TQ 128
#define TK 32

__global__ __launch_bounds__(256, 2)
void mla_attn(const __bf16* __restrict__ Qm, const __bf16* __restrict__ Km,
              const __bf16* __restrict__ Vtg, __bf16* __restrict__ Om) {
  __shared__ __align__(16) __bf16 Kls[2][8 * 512];   // blocks [mt2][kc4]
  __shared__ __align__(16) __bf16 Vls[3][8 * 512];   // blocks [dt8]
  __shared__ __align__(16) __bf16 Ps [2][8 * 512];   // blocks [qg8]
  __shared__ float Lbuf[2][TQ];

  const int t    = threadIdx.x;
  const int wave = t >> 6, lane = t & 63;
  const int quad = lane >> 4, l16 = lane & 15;
  const int wq = wave >> 1, wk = wave & 1, wd = wave & 1;
  const int h = blockIdx.y, b = blockIdx.z;
  const int q0 = blockIdx.x * TQ;
  const size_t kbase  = (size_t)b * SEQ * DMODEL + (size_t)h * DH;
  const size_t vtbase = ((size_t)b * DMODEL + (size_t)h * DH) * SEQ;
  const size_t obase  = (size_t)b * SEQ * DMODEL + (size_t)h * DH;

  // Q fragments (B-operand: n=q=l16, k=quad*8+j), 4 q-tiles x 4 k-chunks
  bf16x8_t qf[4][4];
  #pragma unroll
  for (int nt = 0; nt < 4; ++nt) {
    const __bf16* qp = Qm + ((size_t)b * SEQ + q0 + wq * 64 + nt * 16 + l16) * NQZ
                       + (size_t)h * DH + quad * 8;
    #pragma unroll
    for (int kc = 0; kc < 4; ++kc)
      qf[nt][kc] = *(const bf16x8_t*)(qp + kc * 32);
  }

  auto stage = [&](int tile) {
    int kt0 = tile * TK;
    __bf16* Kd = Kls[tile & 1];
    __bf16* Vd = Vls[tile % 3];
    #pragma unroll
    for (int i2 = 0; i2 < 2; ++i2) {
      int bidx = wave * 2 + i2;   // 0..7
      int mt = bidx >> 2, kc = bidx & 3;
      async_copy16(Km + kbase + (size_t)(kt0 + mt * 16 + l16) * DMODEL + kc * 32 + quad * 8,
                   Kd + bidx * 512 + lane * 8);
      async_copy16(Vtg + vtbase + (size_t)(bidx * 16 + l16) * SEQ + kt0 + quad * 8,
                   Vd + bidx * 512 + lane * 8);
    }
  };

  f32x4_t acc_o[4][4] = {};
  float l_part[4] = {0.f, 0.f, 0.f, 0.f};

  auto pv = [&](const __bf16* Pd, const __bf16* Vd) {
    bf16x8_t pf[4];
    #pragma unroll
    for (int mq = 0; mq < 4; ++mq)
      pf[mq] = *(const bf16x8_t*)(Pd + (wq * 4 + mq) * 512 + lane * 8);
    #pragma unroll
    for (int nd = 0; nd < 4; ++nd) {
      bf16x8_t vf = *(const bf16x8_t*)(Vd + (wd * 4 + nd) * 512 + lane * 8);
      #pragma unroll
      for (int mq = 0; mq < 4; ++mq)
        acc_o[mq][nd] = __builtin_amdgcn_mfma_f32_16x16x32_bf16(pf[mq], vf, acc_o[mq][nd], 0, 0, 0);
    }
  };

  stage(0);

  for (int it = 0; it < SEQ / TK; ++it) {
    __syncthreads();   // drains tile-it DMA; makes Ps(it-1) visible
    if (it + 1 < SEQ / TK) stage(it + 1);          // in flight until next barrier
    if (it > 0) pv(Ps[(it - 1) & 1], Vls[(it - 1) % 3]);

    // ---- QK(it): S^T[16k x 64q] = K · Q^T  (wave's wk key-half of the 32-key tile)
    f32x4_t acc_s[4] = {};
    const __bf16* Kb = Kls[it & 1];
    #pragma unroll
    for (int kc = 0; kc < 4; ++kc) {
      bf16x8_t kf = *(const bf16x8_t*)(Kb + (wk * 4 + kc) * 512 + lane * 8);
      #pragma unroll
      for (int nt = 0; nt < 4; ++nt)
        acc_s[nt] = __builtin_amdgcn_mfma_f32_16x16x32_bf16(kf, qf[nt][kc], acc_s[nt], 0, 0, 0);
    }

    // ---- exp2 + P write (C-layout -> A-frag-block layout, b64 stores)
    __bf16* Pd = Ps[it & 1];
    #pragma unroll
    for (int nt = 0; nt < 4; ++nt) {
      u16x4_t pw;
      float s = 0.f;
      #pragma unroll
      for (int r = 0; r < 4; ++r) {
        float p = EXP2F(fminf(acc_s[nt][r], 80.f));
        s += p;
        pw[r] = f2bf_u16(p);
      }
      l_part[nt] += s;
      *(u16x4_t*)(Pd + (wq * 4 + nt) * 512
                  + ((wk * 2 + (quad >> 1)) * 16 + l16) * 8 + (quad & 1) * 4) = pw;
    }
  }

  __syncthreads();
  pv(Ps[(SEQ / TK - 1) & 1], Vls[(SEQ / TK - 1) % 3]);   // final tile's PV

  // ---- row-sum combine across key-halves + normalize + store
  #pragma unroll
  for (int nt = 0; nt < 4; ++nt) {
    float lp = l_part[nt];
    lp += __shfl_xor(lp, 16);
    lp += __shfl_xor(lp, 32);
    Lbuf[wk][wq * 64 + nt * 16 + l16] = lp;   // 4 quads write same value (benign)
  }
  __syncthreads();
  #pragma unroll
  for (int mq = 0; mq < 4; ++mq) {
    float li[4];
    #pragma unroll
    for (int r = 0; r < 4; ++r) {
      int qq = wq * 64 + mq * 16 + quad * 4 + r;
      li[r] = 1.f / (Lbuf[0][qq] + Lbuf[1][qq]);
    }
    #pragma unroll
    for (int nd = 0; nd < 4; ++nd) {
      int col = wd * 64 + nd * 16 + l16;
      #pragma unroll
      for (int r = 0; r < 4; ++r) {
        int row = q0 + wq * 64 + mq * 16 + quad * 4 + r;
        Om[obase + (size_t)row * DMODEL + col] = (__bf16)(acc_o[mq][nd][r] * li[r]);
      }
    }
  }
}

// ---------------- orchestration ----------------
extern "C" void kernel_launch(void* const* d_in, const int* in_sizes, int n_in,
                              void* d_out, int out_size, void* d_ws, size_t ws_size,
                              hipStream_t stream) {
  (void)in_sizes; (void)n_in; (void)out_size; (void)ws_size;
  const float* x        = (const float*)d_in[0];
  const float* w_latent = (const float*)d_in[1];
  const float* b_latent = (const float*)d_in[2];
  const float* w_q      = (const float*)d_in[3];
  const float* b_q      = (const float*)d_in[4];
  const float* w_k      = (const float*)d_in[5];
  const float* b_k      = (const float*)d_in[6];
  const float* w_v      = (const float*)d_in[7];
  const float* b_v      = (const float*)d_in[8];
  const float* w_o      = (const float*)d_in[9];
  const float* b_o      = (const float*)d_in[10];
  float* out = (float*)d_out;

  __bf16* ws = (__bf16*)d_ws;
  __bf16* xb   = ws; ws += (size_t)MROWS * DMODEL;   // x bf16
  __bf16* wqzt = ws; ws += (size_t)NQZ * DMODEL;     // [w_q^T(scaled) ; w_lat^T]
  __bf16* wkvt = ws; ws += (size_t)NKV * DLAT;       // [w_k^T ; w_v^T]  [4096][512]
  __bf16* wot  = ws; ws += (size_t)DMODEL * DMODEL;  // w_o^T
  __bf16* qzb  = ws; ws += (size_t)MROWS * NQZ;      // [q | z]  [4096][2560]
  __bf16* kb   = ws; ws += (size_t)MROWS * DMODEL;   // k  [4096][2048]
  __bf16* vt   = ws; ws += (size_t)MROWS * DMODEL;   // V^T [b][h*128+d][2048]
  __bf16* ao   = ws; ws += (size_t)MROWS * DMODEL;   // attn out
  float*  bqz  = (float*)ws;                         // [2560]
  float*  bkv  = bqz + NQZ;                          // [4096]

  dim3 blk256(256);
  prep<<<NB_PREP, blk256, 0, stream>>>(x, w_q, w_latent, w_k, w_v, w_o,
                                       b_q, b_latent, b_k, b_v,
                                       xb, wqzt, wkvt, wot, bqz, bkv);

  // fused q|z projection: [4096,2048] @ [2048,2560]
  gemm_bt<__bf16, false><<<dim3(NQZ/BN, MROWS/BM), blk256, 0, stream>>>(
      xb, wqzt, bqz, qzb, nullptr, MROWS, NQZ, DMODEL, DMODEL, NQZ);
  // fused k|v projection: z @ [w_k^T ; w_v^T] : [4096,512] @ [512,4096]
  // cols <2048 -> kb (row-major); cols >=2048 -> vt (transposed)
  gemm_bt<__bf16, true><<<dim3(NKV/BN, MROWS/BM), blk256, 0, stream>>>(
      qzb + DMODEL, wkvt, bkv, kb, vt, MROWS, NKV, DLAT, NQZ, DMODEL);

  mla_attn<<<dim3(SEQ/TQ, H_ATT, NB), blk256, 0, stream>>>(qzb, kb, vt, ao);

  gemm_bt<float, false><<<dim3(DMODEL/BN, MROWS/BM), blk256, 0, stream>>>(
      ao, wot, b_o, out, nullptr, MROWS, DMODEL, DMODEL, DMODEL, DMODEL);
}

// Round 5
// 369.756 us; speedup vs baseline: 1.0441x; 1.0441x over previous
//
#include <hip/hip_runtime.h>
#include <hip/hip_bf16.h>

// ---- problem shape (fixed) ----
#define H_ATT   16
#define DH      128
#define DMODEL  2048
#define DLAT    512
#define NB      2
#define SEQ     2048
#define MROWS   (NB * SEQ)   // 4096
#define NQZ     (DMODEL + DLAT)   // 2560
#define NKV     (2 * DMODEL)      // 4096

// (1/sqrt(128)) * log2(e): folded into w_q/b_q so scores are exp2-ready
#define SCL2 0.12751744f

typedef __bf16          bf16x8_t __attribute__((ext_vector_type(8)));
typedef float           f32x4_t  __attribute__((ext_vector_type(4)));
typedef unsigned short  u16x4_t  __attribute__((ext_vector_type(4)));

#if __has_builtin(__builtin_amdgcn_exp2f)
#define EXP2F(x) __builtin_amdgcn_exp2f(x)
#else
#define EXP2F(x) exp2f(x)
#endif

__device__ __forceinline__ unsigned short f2bf_u16(float f) {
  union { __bf16 b; unsigned short u; } cv; cv.b = (__bf16)f; return cv.u;
}

// async global->LDS, 16B per lane (dest = wave-uniform base + lane*16)
__device__ __forceinline__ void async_copy16(const __bf16* g, __bf16* l) {
  __builtin_amdgcn_global_load_lds(
      (const __attribute__((address_space(1))) unsigned int*)g,
      (__attribute__((address_space(3))) unsigned int*)l, 16, 0, 0);
}

// ---------------- fused prep: x-cast + 5 weight transposes + bias concat ----------------
#define NB_CAST 8192    // (4096*2048/4)/256
#define NB_WQ   4096
#define NB_WL   1024
#define NB_WK   1024
#define NB_WV   1024
#define NB_WO   4096
#define NB_BIAS 26
#define NB_PREP (NB_CAST + NB_WQ + NB_WL + NB_WK + NB_WV + NB_WO + NB_BIAS)

__global__ void prep(const float* __restrict__ x,
                     const float* __restrict__ w_q, const float* __restrict__ w_latent,
                     const float* __restrict__ w_k, const float* __restrict__ w_v,
                     const float* __restrict__ w_o,
                     const float* __restrict__ b_q, const float* __restrict__ b_lat,
                     const float* __restrict__ b_k, const float* __restrict__ b_v,
                     __bf16* __restrict__ xb, __bf16* __restrict__ wqzt,
                     __bf16* __restrict__ wkvt, __bf16* __restrict__ wot,
                     float* __restrict__ bqz, float* __restrict__ bkv) {
  __shared__ float tile[32][33];
  int bi = blockIdx.x;
  int t  = threadIdx.x;

  if (bi < NB_CAST) {                       // ---- cast x -> bf16
    int i = bi * 256 + t;
    float4 v = ((const float4*)x)[i];
    ushort4 o;
    o.x = f2bf_u16(v.x); o.y = f2bf_u16(v.y); o.z = f2bf_u16(v.z); o.w = f2bf_u16(v.w);
    ((ushort4*)xb)[i] = o;
    return;
  }
  bi -= NB_CAST;

  const float* in = nullptr; __bf16* out = nullptr;
  int R = 0, C = 0, bx = 0, by = 0; float scale = 1.f;
  if (bi < NB_WQ) {                         // ---- w_q^T (scaled)
    in = w_q; out = wqzt; R = DMODEL; C = DMODEL; scale = SCL2;
    bx = bi & 63; by = bi >> 6;
  } else if ((bi -= NB_WQ) < NB_WL) {       // ---- w_latent^T
    in = w_latent; out = wqzt + (size_t)DMODEL * DMODEL; R = DMODEL; C = DLAT;
    bx = bi & 15; by = bi >> 4;
  } else if ((bi -= NB_WL) < NB_WK) {       // ---- w_k^T per head
    int h = bi >> 6, rem = bi & 63;
    in = w_k + (size_t)h * DLAT * DH; out = wkvt + (size_t)h * DH * DLAT;
    R = DLAT; C = DH; bx = rem & 3; by = rem >> 2;
  } else if ((bi -= NB_WK) < NB_WV) {       // ---- w_v^T per head
    int h = bi >> 6, rem = bi & 63;
    in = w_v + (size_t)h * DLAT * DH;
    out = wkvt + (size_t)DMODEL * DLAT + (size_t)h * DH * DLAT;
    R = DLAT; C = DH; bx = rem & 3; by = rem >> 2;
  } else if ((bi -= NB_WV) < NB_WO) {       // ---- w_o^T
    in = w_o; out = wot; R = DMODEL; C = DMODEL;
    bx = bi & 63; by = bi >> 6;
  } else {                                  // ---- biases
    bi -= NB_WO;
    int idx = bi * 256 + t;
    if (idx < DMODEL)                bqz[idx] = b_q[idx] * SCL2;
    else if (idx < NQZ)              bqz[idx] = b_lat[idx - DMODEL];
    else if (idx < NQZ + DMODEL)     bkv[idx - NQZ] = b_k[idx - NQZ];
    else if (idx < NQZ + NKV)        bkv[idx - NQZ] = b_v[idx - NQZ - DMODEL];
    return;
  }

  int tx = t & 31, ty = t >> 5;   // (32,8)
  const float* ip = in + (size_t)(by * 32) * C + bx * 32;
  #pragma unroll
  for (int i = 0; i < 4; ++i)
    tile[ty + i * 8][tx] = ip[(size_t)(ty + i * 8) * C + tx];
  __syncthreads();
  __bf16* op = out + (size_t)(bx * 32) * R + by * 32;
  #pragma unroll
  for (int i = 0; i < 4; ++i)
    op[(size_t)(ty + i * 8) * R + tx] = (__bf16)(tile[tx][ty + i * 8] * scale);
}

// ---------------- GEMM (m97 structure): C[M,N] = A[M,K] @ Bt[N,K]^T + bias[N] ----------------
#define BM 128
#define BN 128
#define BK 32

__device__ __forceinline__ void storec(float*  p, float v) { *p = v; }
__device__ __forceinline__ void storec(__bf16* p, float v) { *p = (__bf16)v; }

template <typename OutT, bool KVDUAL>
__global__ __launch_bounds__(256, 2)
void gemm_bt(const __bf16* __restrict__ A, const __bf16* __restrict__ Bt,
             const float* __restrict__ bias, OutT* __restrict__ C,
             __bf16* __restrict__ Cvt,
             int M, int N, int K, int lda, int ldc) {
  __shared__ __align__(16) __bf16 As[BM * BK];
  __shared__ __align__(16) __bf16 Bs[BN * BK];
  const int t    = threadIdx.x;
  const int wave = t >> 6, lane = t & 63;
  const int quad = lane >> 4, l16 = lane & 15;
  const int wm = (wave >> 1) * 64, wn = (wave & 1) * 64;
  const int row0 = blockIdx.y * BM, col0 = blockIdx.x * BN;
  const int srow = t >> 2, skc = t & 3;

  const __bf16* Ag  = A  + (size_t)(row0 + srow)      * lda + skc * 8;
  const __bf16* Ag2 = A  + (size_t)(row0 + srow + 64) * lda + skc * 8;
  const __bf16* Bg  = Bt + (size_t)(col0 + srow)      * K   + skc * 8;
  const __bf16* Bg2 = Bt + (size_t)(col0 + srow + 64) * K   + skc * 8;
  __bf16* Al  = As + t * 8;
  __bf16* Al2 = As + 2048 + t * 8;
  __bf16* Bl  = Bs + t * 8;
  __bf16* Bl2 = Bs + 2048 + t * 8;

  f32x4_t acc[4][4] = {};

  for (int k0 = 0; k0 < K; k0 += BK) {
    async_copy16(Ag  + k0, Al);
    async_copy16(Ag2 + k0, Al2);
    async_copy16(Bg  + k0, Bl);
    async_copy16(Bg2 + k0, Bl2);
    __syncthreads();
    bf16x8_t af[4], bfr[4];
    #pragma unroll
    for (int i = 0; i < 4; ++i)
      af[i] = *(const bf16x8_t*)(As + (wm + i * 16 + l16) * BK + quad * 8);
    #pragma unroll
    for (int j = 0; j < 4; ++j)
      bfr[j] = *(const bf16x8_t*)(Bs + (wn + j * 16 + l16) * BK + quad * 8);
    #pragma unroll
    for (int i = 0; i < 4; ++i)
      #pragma unroll
      for (int j = 0; j < 4; ++j)
        acc[i][j] = __builtin_amdgcn_mfma_f32_16x16x32_bf16(af[i], bfr[j], acc[i][j], 0, 0, 0);
    __syncthreads();
  }

  const bool vmode = KVDUAL && (col0 >= DMODEL);
  #pragma unroll
  for (int j = 0; j < 4; ++j) {
    int col = col0 + wn + j * 16 + l16;
    float bj = bias[col];
    #pragma unroll
    for (int i = 0; i < 4; ++i) {
      int row = row0 + wm + i * 16 + quad * 4;
      if (vmode) {
        u16x4_t pw;
        #pragma unroll
        for (int r = 0; r < 4; ++r) pw[r] = f2bf_u16(acc[i][j][r] + bj);
        size_t bb = (size_t)(row >> 11);
        int s = row & (SEQ - 1);
        *(u16x4_t*)(Cvt + bb * ((size_t)DMODEL * SEQ) + (size_t)(col - DMODEL) * SEQ + s) = pw;
      } else {
        #pragma unroll
        for (int r = 0; r < 4; ++r)
          storec(&C[(size_t)(row + r) * ldc + col], acc[i][j][r] + bj);
      }
    }
  }
}

// ---------------- flash attention v5: P stays in registers ----------------
// grid (SEQ/128, H, B), block 256 (4 waves): wq = wave>>1 (q-half, 64q),
// wk = wave&1 (key-half, 32 keys of each 64-key tile).
// K rows are staged PERMUTED: LDS tile-row p (p=[mt|quad|r]) holds actual key
// kappa(p)=[quad|mt|r] = quad*8+mt*4+r. Then S^T=K.Q^T C-layout puts, in lane
// (quad,l16), scores for actual keys quad*8+mt*4+r -- exactly the PV B-operand
// fragment order (k=quad*8+j, j=mt*4+r). So exp2+pack feeds PV MFMAs directly
// from registers: no P LDS round-trip, no cross-lane ops, 1 barrier/iter.
// Each wave accumulates partial O^T[128d x 64q] for its key-half; the two
// key-halves are combined once at the end through LDS (reusing K/V space).
#define TQ 128
#define TK 64
// smem layout (bytes): [0,32768) K bufs (2x16KB), [32768,65536) V bufs (2x16KB)
// epilogue reuse: [0,67584) Cmb fp32 2 x 64q x (128+4)d ; [67584,68608) Lbuf
#define SMEM_BYTES 68608
#define CMB_ST 132

__global__ __launch_bounds__(256, 2)
void mla_attn(const __bf16* __restrict__ Qm, const __bf16* __restrict__ Km,
              const __bf16* __restrict__ Vtg, __bf16* __restrict__ Om) {
  __shared__ __align__(16) char smem_raw[SMEM_BYTES];

  const int t    = threadIdx.x;
  const int wave = t >> 6, lane = t & 63;
  const int quad = lane >> 4, l16 = lane & 15;
  const int wq = wave >> 1, wk = wave & 1;
  const int h = blockIdx.y, b = blockIdx.z;
  const int q0 = blockIdx.x * TQ;
  const size_t kbase  = (size_t)b * SEQ * DMODEL + (size_t)h * DH;
  const size_t vtbase = ((size_t)b * DMODEL + (size_t)h * DH) * SEQ;
  const size_t obase  = (size_t)b * SEQ * DMODEL + (size_t)h * DH;

  // Q fragments (B-operand: n=q=l16, k=quad*8+j), this wave's 64-q half
  bf16x8_t qf[4][4];
  #pragma unroll
  for (int nt = 0; nt < 4; ++nt) {
    const __bf16* qp = Qm + ((size_t)b * SEQ + q0 + wq * 64 + nt * 16 + l16) * NQZ
                       + (size_t)h * DH + quad * 8;
    #pragma unroll
    for (int kc = 0; kc < 4; ++kc)
      qf[nt][kc] = *(const bf16x8_t*)(qp + kc * 32);
  }

  // stage tile -> K/V buffers (16 x 1KB blocks each); K rows permuted by kappa
  auto stage = [&](int tile) {
    int kt0 = tile * TK;
    __bf16* Kd = (__bf16*)smem_raw + (tile & 1) * 8192;
    __bf16* Vd = (__bf16*)smem_raw + 16384 + (tile & 1) * 8192;
    #pragma unroll
    for (int i2 = 0; i2 < 4; ++i2) {
      int bidx = wave * 4 + i2;                       // 0..15
      int wk2 = bidx >> 3, mt = (bidx >> 2) & 1, kc = bidx & 3;
      int keyrow = kt0 + wk2 * 32 + (l16 >> 2) * 8 + mt * 4 + (l16 & 3);  // kappa
      async_copy16(Km + kbase + (size_t)keyrow * DMODEL + kc * 32 + quad * 8,
                   Kd + bidx * 512 + lane * 8);
      int dt = bidx & 7;                              // V block: (bidx>>3)=wk2, dt
      async_copy16(Vtg + vtbase + (size_t)(dt * 16 + l16) * SEQ + kt0 + wk2 * 32 + quad * 8,
                   Vd + bidx * 512 + lane * 8);
    }
  };

  f32x4_t acc_o[8][4] = {};           // O^T partial: [dt][nt], m=d, n=q
  float l_part[4] = {0.f, 0.f, 0.f, 0.f};

  stage(0);

  for (int it = 0; it < SEQ / TK; ++it) {
    __syncthreads();                   // drains tile-it DMA
    if (it + 1 < SEQ / TK) stage(it + 1);
    const __bf16* Kb = (const __bf16*)smem_raw + (it & 1) * 8192;
    const __bf16* Vb = (const __bf16*)smem_raw + 16384 + (it & 1) * 8192;

    // ---- QK + exp2, mt-split to cap register pressure; pack into PV B-frags
    union { bf16x8_t v8; unsigned short u[8]; } pfr[4];
    #pragma unroll
    for (int mt = 0; mt < 2; ++mt) {
      f32x4_t acc_s[4] = {};
      #pragma unroll
      for (int kc = 0; kc < 4; ++kc) {
        bf16x8_t kf = *(const bf16x8_t*)(Kb + ((wk * 2 + mt) * 4 + kc) * 512 + lane * 8);
        #pragma unroll
        for (int nt = 0; nt < 4; ++nt)
          acc_s[nt] = __builtin_amdgcn_mfma_f32_16x16x32_bf16(kf, qf[nt][kc], acc_s[nt], 0, 0, 0);
      }
      #pragma unroll
      for (int nt = 0; nt < 4; ++nt) {
        float s = 0.f;
        #pragma unroll
        for (int r = 0; r < 4; ++r) {
          float p = EXP2F(fminf(acc_s[nt][r], 80.f));
          s += p;
          pfr[nt].u[mt * 4 + r] = f2bf_u16(p);
        }
        l_part[nt] += s;
      }
    }

    // ---- PV: O^T[128d x 64q] += V^T[128d x 32k_own] . P[32k_own x 64q]
    #pragma unroll
    for (int dt = 0; dt < 8; ++dt) {
      bf16x8_t vf = *(const bf16x8_t*)(Vb + (wk * 8 + dt) * 512 + lane * 8);
      #pragma unroll
      for (int nt = 0; nt < 4; ++nt)
        acc_o[dt][nt] = __builtin_amdgcn_mfma_f32_16x16x32_bf16(vf, pfr[nt].v8, acc_o[dt][nt], 0, 0, 0);
    }
  }

  // ---- epilogue: reduce l across quads, combine key-halves via LDS, store
  float* Lb = (float*)(smem_raw + 67584);             // [2][128]
  #pragma unroll
  for (int nt = 0; nt < 4; ++nt) {
    float lp = l_part[nt];
    lp += __shfl_xor(lp, 16);
    lp += __shfl_xor(lp, 32);
    Lb[wk * 128 + wq * 64 + nt * 16 + l16] = lp;      // 4 quads same value (benign)
  }
  __syncthreads();                                    // all loop LDS reads done

  float* Cmb = (float*)smem_raw + (size_t)wq * 64 * CMB_ST;   // [q][d] fp32, padded
  if (wk) {
    #pragma unroll
    for (int dt = 0; dt < 8; ++dt)
      #pragma unroll
      for (int nt = 0; nt < 4; ++nt)
        *(f32x4_t*)(Cmb + (nt * 16 + l16) * CMB_ST + dt * 16 + quad * 4) = acc_o[dt][nt];
  }
  __syncthreads();
  if (!wk) {
    float linv[4];
    #pragma unroll
    for (int nt = 0; nt < 4; ++nt) {
      int qq = wq * 64 + nt * 16 + l16;
      linv[nt] = 1.f / (Lb[qq] + Lb[128 + qq]);
    }
    #pragma unroll
    for (int dt = 0; dt < 8; ++dt)
      #pragma unroll
      for (int nt = 0; nt < 4; ++nt) {
        f32x4_t o = *(const f32x4_t*)(Cmb + (nt * 16 + l16) * CMB_ST + dt * 16 + quad * 4);
        u16x4_t st;
        #pragma unroll
        for (int r = 0; r < 4; ++r)
          st[r] = f2bf_u16((acc_o[dt][nt][r] + o[r]) * linv[nt]);
        *(u16x4_t*)(Om + obase + (size_t)(q0 + wq * 64 + nt * 16 + l16) * DMODEL
                    + dt * 16 + quad * 4) = st;
      }
  }
}

// ---------------- orchestration ----------------
extern "C" void kernel_launch(void* const* d_in, const int* in_sizes, int n_in,
                              void* d_out, int out_size, void* d_ws, size_t ws_size,
                              hipStream_t stream) {
  (void)in_sizes; (void)n_in; (void)out_size; (void)ws_size;
  const float* x        = (const float*)d_in[0];
  const float* w_latent = (const float*)d_in[1];
  const float* b_latent = (const float*)d_in[2];
  const float* w_q      = (const float*)d_in[3];
  const float* b_q      = (const float*)d_in[4];
  const float* w_k      = (const float*)d_in[5];
  const float* b_k      = (const float*)d_in[6];
  const float* w_v      = (const float*)d_in[7];
  const float* b_v      = (const float*)d_in[8];
  const float* w_o      = (const float*)d_in[9];
  const float* b_o      = (const float*)d_in[10];
  float* out = (float*)d_out;

  __bf16* ws = (__bf16*)d_ws;
  __bf16* xb   = ws; ws += (size_t)MROWS * DMODEL;
  __bf16* wqzt = ws; ws += (size_t)NQZ * DMODEL;
  __bf16* wkvt = ws; ws += (size_t)NKV * DLAT;
  __bf16* wot  = ws; ws += (size_t)DMODEL * DMODEL;
  __bf16* qzb  = ws; ws += (size_t)MROWS * NQZ;
  __bf16* kb   = ws; ws += (size_t)MROWS * DMODEL;
  __bf16* vt   = ws; ws += (size_t)MROWS * DMODEL;
  __bf16* ao   = ws; ws += (size_t)MROWS * DMODEL;
  float*  bqz  = (float*)ws;
  float*  bkv  = bqz + NQZ;

  dim3 blk256(256);
  prep<<<NB_PREP, blk256, 0, stream>>>(x, w_q, w_latent, w_k, w_v, w_o,
                                       b_q, b_latent, b_k, b_v,
                                       xb, wqzt, wkvt, wot, bqz, bkv);

  gemm_bt<__bf16, false><<<dim3(NQZ/BN, MROWS/BM), blk256, 0, stream>>>(
      xb, wqzt, bqz, qzb, nullptr, MROWS, NQZ, DMODEL, DMODEL, NQZ);
  gemm_bt<__bf16, true><<<dim3(NKV/BN, MROWS/BM), blk256, 0, stream>>>(
      qzb + DMODEL, wkvt, bkv, kb, vt, MROWS, NKV, DLAT, NQZ, DMODEL);

  mla_attn<<<dim3(SEQ/TQ, H_ATT, NB), blk256, 0, stream>>>(qzb, kb, vt, ao);

  gemm_bt<float, false><<<dim3(DMODEL/BN, MROWS/BM), blk256, 0, stream>>>(
      ao, wot, b_o, out, nullptr, MROWS, DMODEL, DMODEL, DMODEL, DMODEL);
}

// Round 6
// 344.352 us; speedup vs baseline: 1.1211x; 1.0738x over previous
//
#include <hip/hip_runtime.h>
#include <hip/hip_bf16.h>

// ---- problem shape (fixed) ----
#define H_ATT   16
#define DH      128
#define DMODEL  2048
#define DLAT    512
#define NB      2
#define SEQ     2048
#define MROWS   (NB * SEQ)   // 4096
#define NQZ     (DMODEL + DLAT)   // 2560
#define NKV     (2 * DMODEL)      // 4096

// (1/sqrt(128)) * log2(e): folded into w_q/b_q so scores are exp2-ready
#define SCL2 0.12751744f

typedef __bf16          bf16x8_t __attribute__((ext_vector_type(8)));
typedef float           f32x4_t  __attribute__((ext_vector_type(4)));
typedef unsigned short  u16x4_t  __attribute__((ext_vector_type(4)));

#if __has_builtin(__builtin_amdgcn_exp2f)
#define EXP2F(x) __builtin_amdgcn_exp2f(x)
#else
#define EXP2F(x) exp2f(x)
#endif

__device__ __forceinline__ unsigned short f2bf_u16(float f) {
  union { __bf16 b; unsigned short u; } cv; cv.b = (__bf16)f; return cv.u;
}

// async global->LDS, 16B per lane (dest = wave-uniform base + lane*16)
__device__ __forceinline__ void async_copy16(const __bf16* g, __bf16* l) {
  __builtin_amdgcn_global_load_lds(
      (const __attribute__((address_space(1))) unsigned int*)g,
      (__attribute__((address_space(3))) unsigned int*)l, 16, 0, 0);
}

// ---------------- fused prep: x-cast + 5 weight transposes + bias concat ----------------
#define NB_CAST 8192    // (4096*2048/4)/256
#define NB_WQ   4096
#define NB_WL   1024
#define NB_WK   1024
#define NB_WV   1024
#define NB_WO   4096
#define NB_BIAS 26
#define NB_PREP (NB_CAST + NB_WQ + NB_WL + NB_WK + NB_WV + NB_WO + NB_BIAS)

__global__ void prep(const float* __restrict__ x,
                     const float* __restrict__ w_q, const float* __restrict__ w_latent,
                     const float* __restrict__ w_k, const float* __restrict__ w_v,
                     const float* __restrict__ w_o,
                     const float* __restrict__ b_q, const float* __restrict__ b_lat,
                     const float* __restrict__ b_k, const float* __restrict__ b_v,
                     __bf16* __restrict__ xb, __bf16* __restrict__ wqzt,
                     __bf16* __restrict__ wkvt, __bf16* __restrict__ wot,
                     float* __restrict__ bqz, float* __restrict__ bkv) {
  __shared__ float tile[32][33];
  int bi = blockIdx.x;
  int t  = threadIdx.x;

  if (bi < NB_CAST) {                       // ---- cast x -> bf16
    int i = bi * 256 + t;
    float4 v = ((const float4*)x)[i];
    ushort4 o;
    o.x = f2bf_u16(v.x); o.y = f2bf_u16(v.y); o.z = f2bf_u16(v.z); o.w = f2bf_u16(v.w);
    ((ushort4*)xb)[i] = o;
    return;
  }
  bi -= NB_CAST;

  const float* in = nullptr; __bf16* out = nullptr;
  int R = 0, C = 0, bx = 0, by = 0; float scale = 1.f;
  if (bi < NB_WQ) {                         // ---- w_q^T (scaled)
    in = w_q; out = wqzt; R = DMODEL; C = DMODEL; scale = SCL2;
    bx = bi & 63; by = bi >> 6;
  } else if ((bi -= NB_WQ) < NB_WL) {       // ---- w_latent^T
    in = w_latent; out = wqzt + (size_t)DMODEL * DMODEL; R = DMODEL; C = DLAT;
    bx = bi & 15; by = bi >> 4;
  } else if ((bi -= NB_WL) < NB_WK) {       // ---- w_k^T per head
    int h = bi >> 6, rem = bi & 63;
    in = w_k + (size_t)h * DLAT * DH; out = wkvt + (size_t)h * DH * DLAT;
    R = DLAT; C = DH; bx = rem & 3; by = rem >> 2;
  } else if ((bi -= NB_WK) < NB_WV) {       // ---- w_v^T per head
    int h = bi >> 6, rem = bi & 63;
    in = w_v + (size_t)h * DLAT * DH;
    out = wkvt + (size_t)DMODEL * DLAT + (size_t)h * DH * DLAT;
    R = DLAT; C = DH; bx = rem & 3; by = rem >> 2;
  } else if ((bi -= NB_WV) < NB_WO) {       // ---- w_o^T
    in = w_o; out = wot; R = DMODEL; C = DMODEL;
    bx = bi & 63; by = bi >> 6;
  } else {                                  // ---- biases
    bi -= NB_WO;
    int idx = bi * 256 + t;
    if (idx < DMODEL)                bqz[idx] = b_q[idx] * SCL2;
    else if (idx < NQZ)              bqz[idx] = b_lat[idx - DMODEL];
    else if (idx < NQZ + DMODEL)     bkv[idx - NQZ] = b_k[idx - NQZ];
    else if (idx < NQZ + NKV)        bkv[idx - NQZ] = b_v[idx - NQZ - DMODEL];
    return;
  }

  int tx = t & 31, ty = t >> 5;   // (32,8)
  const float* ip = in + (size_t)(by * 32) * C + bx * 32;
  #pragma unroll
  for (int i = 0; i < 4; ++i)
    tile[ty + i * 8][tx] = ip[(size_t)(ty + i * 8) * C + tx];
  __syncthreads();
  __bf16* op = out + (size_t)(bx * 32) * R + by * 32;
  #pragma unroll
  for (int i = 0; i < 4; ++i)
    op[(size_t)(ty + i * 8) * R + tx] = (__bf16)(tile[tx][ty + i * 8] * scale);
}

// ---------------- GEMM (m97 structure): C[M,N] = A[M,K] @ Bt[N,K]^T + bias[N] ----------------
#define BM 128
#define BN 128
#define BK 32

__device__ __forceinline__ void storec(float*  p, float v) { *p = v; }
__device__ __forceinline__ void storec(__bf16* p, float v) { *p = (__bf16)v; }

template <typename OutT, bool KVDUAL>
__global__ __launch_bounds__(256, 2)
void gemm_bt(const __bf16* __restrict__ A, const __bf16* __restrict__ Bt,
             const float* __restrict__ bias, OutT* __restrict__ C,
             __bf16* __restrict__ Cvt,
             int M, int N, int K, int lda, int ldc) {
  __shared__ __align__(16) __bf16 As[BM * BK];
  __shared__ __align__(16) __bf16 Bs[BN * BK];
  const int t    = threadIdx.x;
  const int wave = t >> 6, lane = t & 63;
  const int quad = lane >> 4, l16 = lane & 15;
  const int wm = (wave >> 1) * 64, wn = (wave & 1) * 64;
  const int row0 = blockIdx.y * BM, col0 = blockIdx.x * BN;
  const int srow = t >> 2, skc = t & 3;

  const __bf16* Ag  = A  + (size_t)(row0 + srow)      * lda + skc * 8;
  const __bf16* Ag2 = A  + (size_t)(row0 + srow + 64) * lda + skc * 8;
  const __bf16* Bg  = Bt + (size_t)(col0 + srow)      * K   + skc * 8;
  const __bf16* Bg2 = Bt + (size_t)(col0 + srow + 64) * K   + skc * 8;
  __bf16* Al  = As + t * 8;
  __bf16* Al2 = As + 2048 + t * 8;
  __bf16* Bl  = Bs + t * 8;
  __bf16* Bl2 = Bs + 2048 + t * 8;

  f32x4_t acc[4][4] = {};

  for (int k0 = 0; k0 < K; k0 += BK) {
    async_copy16(Ag  + k0, Al);
    async_copy16(Ag2 + k0, Al2);
    async_copy16(Bg  + k0, Bl);
    async_copy16(Bg2 + k0, Bl2);
    __syncthreads();
    bf16x8_t af[4], bfr[4];
    #pragma unroll
    for (int i = 0; i < 4; ++i)
      af[i] = *(const bf16x8_t*)(As + (wm + i * 16 + l16) * BK + quad * 8);
    #pragma unroll
    for (int j = 0; j < 4; ++j)
      bfr[j] = *(const bf16x8_t*)(Bs + (wn + j * 16 + l16) * BK + quad * 8);
    #pragma unroll
    for (int i = 0; i < 4; ++i)
      #pragma unroll
      for (int j = 0; j < 4; ++j)
        acc[i][j] = __builtin_amdgcn_mfma_f32_16x16x32_bf16(af[i], bfr[j], acc[i][j], 0, 0, 0);
    __syncthreads();
  }

  const bool vmode = KVDUAL && (col0 >= DMODEL);
  #pragma unroll
  for (int j = 0; j < 4; ++j) {
    int col = col0 + wn + j * 16 + l16;
    float bj = bias[col];
    #pragma unroll
    for (int i = 0; i < 4; ++i) {
      int row = row0 + wm + i * 16 + quad * 4;
      if (vmode) {
        u16x4_t pw;
        #pragma unroll
        for (int r = 0; r < 4; ++r) pw[r] = f2bf_u16(acc[i][j][r] + bj);
        size_t bb = (size_t)(row >> 11);
        int s = row & (SEQ - 1);
        *(u16x4_t*)(Cvt + bb * ((size_t)DMODEL * SEQ) + (size_t)(col - DMODEL) * SEQ + s) = pw;
      } else {
        #pragma unroll
        for (int r = 0; r < 4; ++r)
          storec(&C[(size_t)(row + r) * ldc + col], acc[i][j][r] + bj);
      }
    }
  }
}

// ---------------- flash attention (v3 structure, proven 92.8us) + XCD swizzle ----------------
// flat grid 512; decode so each XCD (blockIdx%8) owns 4 (b,h) pairs -> K/V working
// set 4MB = one XCD L2. 4 waves: wq=wave>>1 (64q), wk=wd=wave&1.
// LDS in 1KB fragment-blocks (64 lanes x 16B, exact frag-read order) -> stride-1
// conflict-free ds_read_b128 AND direct global_load_lds staging (K and pre-transposed V).
#define TQ 128
#define TK 64

__global__ __launch_bounds__(256, 2)
void mla_attn(const __bf16* __restrict__ Qm, const __bf16* __restrict__ Km,
              const __bf16* __restrict__ Vtg, __bf16* __restrict__ Om) {
  __shared__ __align__(16) __bf16 Kls[16 * 512];      // blocks [mt4][kc4]
  __shared__ __align__(16) __bf16 Vls[2][16 * 512];   // blocks [dt8][ks2], double-buffered
  __shared__ __align__(16) __bf16 Ps [16 * 512];      // blocks [qg8][ks2]
  __shared__ float Lbuf[2][TQ];

  const int t    = threadIdx.x;
  const int wave = t >> 6, lane = t & 63;
  const int quad = lane >> 4, l16 = lane & 15;
  const int wq = wave >> 1, wk = wave & 1, wd = wave & 1;
  // XCD-aware decode: lin%8 = XCD; each XCD gets head-batches [xcd*4, xcd*4+4)
  const int lin  = blockIdx.x;
  const int xcd  = lin & 7, slot = lin >> 3;       // slot 0..63
  const int hb   = xcd * 4 + (slot >> 4);          // 0..31
  const int b    = hb >> 4, h = hb & 15;
  const int q0   = (slot & 15) * TQ;
  const size_t kbase  = (size_t)b * SEQ * DMODEL + (size_t)h * DH;
  const size_t vtbase = ((size_t)b * DMODEL + (size_t)h * DH) * SEQ;
  const size_t obase  = (size_t)b * SEQ * DMODEL + (size_t)h * DH;

  // Q fragments (B-operand: n=q=l16, k=quad*8+j), 4 q-tiles x 4 k-chunks
  bf16x8_t qf[4][4];
  #pragma unroll
  for (int nt = 0; nt < 4; ++nt) {
    const __bf16* qp = Qm + ((size_t)b * SEQ + q0 + wq * 64 + nt * 16 + l16) * NQZ
                       + (size_t)h * DH + quad * 8;
    #pragma unroll
    for (int kc = 0; kc < 4; ++kc)
      qf[nt][kc] = *(const bf16x8_t*)(qp + kc * 32);
  }

  // stage K(kt0) into Kls and V(kt0) into Vls[vbuf]; 8 async per wave, zero VALU pack
  auto stage = [&](int kt0, int vbuf) {
    #pragma unroll
    for (int i2 = 0; i2 < 4; ++i2) {
      int bidx = wave * 4 + i2;
      int mt = bidx >> 2, kc = bidx & 3;
      async_copy16(Km + kbase + (size_t)(kt0 + mt * 16 + l16) * DMODEL + kc * 32 + quad * 8,
                   Kls + bidx * 512 + lane * 8);
      int dt = bidx >> 1, ks = bidx & 1;
      async_copy16(Vtg + vtbase + (size_t)(dt * 16 + l16) * SEQ + kt0 + ks * 32 + quad * 8,
                   Vls[vbuf] + bidx * 512 + lane * 8);
    }
  };

  f32x4_t acc_o[4][4] = {};
  float l_part[4] = {0.f, 0.f, 0.f, 0.f};

  stage(0, 0);

  f32x4_t acc_s[2][4];
  for (int it = 0; it < SEQ / TK; ++it) {
    __syncthreads();   // (B): DMA for tile `it` drained; Ps(it-1) visible

    // ---- PV(it-1): O[64q x 64d] += P[64q x 64k] @ V[64k x 64d]
    if (it > 0) {
      const __bf16* Vb = Vls[(it - 1) & 1];
      #pragma unroll
      for (int ks = 0; ks < 2; ++ks) {
        bf16x8_t pf[4];
        #pragma unroll
        for (int mq = 0; mq < 4; ++mq)
          pf[mq] = *(const bf16x8_t*)(Ps + ((wq * 4 + mq) * 2 + ks) * 512 + lane * 8);
        #pragma unroll
        for (int nd = 0; nd < 4; ++nd) {
          bf16x8_t vf = *(const bf16x8_t*)(Vb + ((wd * 4 + nd) * 2 + ks) * 512 + lane * 8);
          #pragma unroll
          for (int mq = 0; mq < 4; ++mq)
            acc_o[mq][nd] = __builtin_amdgcn_mfma_f32_16x16x32_bf16(pf[mq], vf, acc_o[mq][nd], 0, 0, 0);
        }
      }
    }

    // ---- QK(it): S^T[32k x 64q] = K · Q^T  (wave's wk key-half)
    #pragma unroll
    for (int mtl = 0; mtl < 2; ++mtl)
      #pragma unroll
      for (int nt = 0; nt < 4; ++nt)
        acc_s[mtl][nt] = f32x4_t{0.f, 0.f, 0.f, 0.f};
    #pragma unroll
    for (int kc = 0; kc < 4; ++kc)
      #pragma unroll
      for (int mtl = 0; mtl < 2; ++mtl) {
        bf16x8_t kf = *(const bf16x8_t*)(Kls + ((wk * 2 + mtl) * 4 + kc) * 512 + lane * 8);
        #pragma unroll
        for (int nt = 0; nt < 4; ++nt)
          acc_s[mtl][nt] = __builtin_amdgcn_mfma_f32_16x16x32_bf16(kf, qf[nt][kc], acc_s[mtl][nt], 0, 0, 0);
      }

    __syncthreads();   // (A): K reads + PV(it-1) reads done block-wide

    if (it + 1 < SEQ / TK) stage((it + 1) * TK, (it + 1) & 1);  // overlaps with exp below

    // ---- exp2 + P write (C-layout -> A-frag-block layout, b64 stores)
    #pragma unroll
    for (int nt = 0; nt < 4; ++nt) {
      #pragma unroll
      for (int mtl = 0; mtl < 2; ++mtl) {
        u16x4_t pw;
        float s = 0.f;
        #pragma unroll
        for (int r = 0; r < 4; ++r) {
          float p = EXP2F(fminf(acc_s[mtl][nt][r], 80.f));
          s += p;
          pw[r] = f2bf_u16(p);
        }
        l_part[nt] += s;
        *(u16x4_t*)(Ps + ((wq * 4 + nt) * 2 + wk) * 512
                    + ((mtl * 2 + (quad >> 1)) * 16 + l16) * 8 + (quad & 1) * 4) = pw;
      }
    }
  }

  __syncthreads();
  // ---- final PV for the last tile
  {
    const __bf16* Vb = Vls[(SEQ / TK - 1) & 1];
    #pragma unroll
    for (int ks = 0; ks < 2; ++ks) {
      bf16x8_t pf[4];
      #pragma unroll
      for (int mq = 0; mq < 4; ++mq)
        pf[mq] = *(const bf16x8_t*)(Ps + ((wq * 4 + mq) * 2 + ks) * 512 + lane * 8);
      #pragma unroll
      for (int nd = 0; nd < 4; ++nd) {
        bf16x8_t vf = *(const bf16x8_t*)(Vb + ((wd * 4 + nd) * 2 + ks) * 512 + lane * 8);
        #pragma unroll
        for (int mq = 0; mq < 4; ++mq)
          acc_o[mq][nd] = __builtin_amdgcn_mfma_f32_16x16x32_bf16(pf[mq], vf, acc_o[mq][nd], 0, 0, 0);
      }
    }
  }

  // ---- row-sum combine across key-halves + normalize + store
  #pragma unroll
  for (int nt = 0; nt < 4; ++nt) {
    float lp = l_part[nt];
    lp += __shfl_xor(lp, 16);
    lp += __shfl_xor(lp, 32);
    Lbuf[wk][wq * 64 + nt * 16 + l16] = lp;   // 4 quads write same value (benign)
  }
  __syncthreads();
  #pragma unroll
  for (int mq = 0; mq < 4; ++mq) {
    float li[4];
    #pragma unroll
    for (int r = 0; r < 4; ++r) {
      int qq = wq * 64 + mq * 16 + quad * 4 + r;
      li[r] = 1.f / (Lbuf[0][qq] + Lbuf[1][qq]);
    }
    #pragma unroll
    for (int nd = 0; nd < 4; ++nd) {
      int col = wd * 64 + nd * 16 + l16;
      #pragma unroll
      for (int r = 0; r < 4; ++r) {
        int row = q0 + wq * 64 + mq * 16 + quad * 4 + r;
        Om[obase + (size_t)row * DMODEL + col] = (__bf16)(acc_o[mq][nd][r] * li[r]);
      }
    }
  }
}

// ---------------- orchestration ----------------
extern "C" void kernel_launch(void* const* d_in, const int* in_sizes, int n_in,
                              void* d_out, int out_size, void* d_ws, size_t ws_size,
                              hipStream_t stream) {
  (void)in_sizes; (void)n_in; (void)out_size; (void)ws_size;
  const float* x        = (const float*)d_in[0];
  const float* w_latent = (const float*)d_in[1];
  const float* b_latent = (const float*)d_in[2];
  const float* w_q      = (const float*)d_in[3];
  const float* b_q      = (const float*)d_in[4];
  const float* w_k      = (const float*)d_in[5];
  const float* b_k      = (const float*)d_in[6];
  const float* w_v      = (const float*)d_in[7];
  const float* b_v      = (const float*)d_in[8];
  const float* w_o      = (const float*)d_in[9];
  const float* b_o      = (const float*)d_in[10];
  float* out = (float*)d_out;

  __bf16* ws = (__bf16*)d_ws;
  __bf16* xb   = ws; ws += (size_t)MROWS * DMODEL;
  __bf16* wqzt = ws; ws += (size_t)NQZ * DMODEL;
  __bf16* wkvt = ws; ws += (size_t)NKV * DLAT;
  __bf16* wot  = ws; ws += (size_t)DMODEL * DMODEL;
  __bf16* qzb  = ws; ws += (size_t)MROWS * NQZ;
  __bf16* kb   = ws; ws += (size_t)MROWS * DMODEL;
  __bf16* vt   = ws; ws += (size_t)MROWS * DMODEL;
  __bf16* ao   = ws; ws += (size_t)MROWS * DMODEL;
  float*  bqz  = (float*)ws;
  float*  bkv  = bqz + NQZ;

  dim3 blk256(256);
  prep<<<NB_PREP, blk256, 0, stream>>>(x, w_q, w_latent, w_k, w_v, w_o,
                                       b_q, b_latent, b_k, b_v,
                                       xb, wqzt, wkvt, wot, bqz, bkv);

  gemm_bt<__bf16, false><<<dim3(NQZ/BN, MROWS/BM), blk256, 0, stream>>>(
      xb, wqzt, bqz, qzb, nullptr, MROWS, NQZ, DMODEL, DMODEL, NQZ);
  gemm_bt<__bf16, true><<<dim3(NKV/BN, MROWS/BM), blk256, 0, stream>>>(
      qzb + DMODEL, wkvt, bkv, kb, vt, MROWS, NKV, DLAT, NQZ, DMODEL);

  mla_attn<<<dim3(512), blk256, 0, stream>>>(qzb, kb, vt, ao);

  gemm_bt<float, false><<<dim3(DMODEL/BN, MROWS/BM), blk256, 0, stream>>>(
      ao, wot, b_o, out, nullptr, MROWS, DMODEL, DMODEL, DMODEL, DMODEL);
}